// Round 1
// baseline (586.275 us; speedup 1.0000x reference)
//
#include <hip/hip_runtime.h>

// CrossAttention: B=8, C=256, H=W=64, N=4096
// Pipeline: split_w3 (W -> bf16 hi/lo) -> proj_kernel (Q/K/V via hi/lo MFMA)
//           -> attn_kernel (flash attention, swapped-QK 16x16x32 MFMA).
// Workspace: qt_hi/qt_lo/kt_hi/kt_lo/vv (5 x 16.78MB) + Wsplit (768KB) ~= 84.7MB.

#define C_DIM 256
#define N_DIM 4096

using f32x4 = __attribute__((ext_vector_type(4))) float;
using s16x8 = __attribute__((ext_vector_type(8))) short;

__device__ __forceinline__ unsigned short f2bf(float f) {
  unsigned int u = __builtin_bit_cast(unsigned int, f);
  u += 0x7FFFu + ((u >> 16) & 1u);   // RNE
  return (unsigned short)(u >> 16);
}
__device__ __forceinline__ float bf2f(unsigned short h) {
  unsigned int u = ((unsigned int)h) << 16;
  return __builtin_bit_cast(float, u);
}
__device__ __forceinline__ f32x4 mfma16(s16x8 a, s16x8 b, f32x4 c) {
  return __builtin_amdgcn_mfma_f32_16x16x32_bf16(a, b, c, 0, 0, 0);
}

// ---------------- kernel 1: split W into bf16 hi/lo planes ----------------
__global__ __launch_bounds__(256) void split_w3(const float* __restrict__ wq,
                                                const float* __restrict__ wk,
                                                const float* __restrict__ wv,
                                                unsigned short* __restrict__ dst) {
  int i = blockIdx.x * 256 + threadIdx.x;  // 0..65535
  int m = blockIdx.y;                      // 0..2
  const float* w = (m == 0) ? wq : ((m == 1) ? wk : wv);
  float x = w[i];
  unsigned short h = f2bf(x);
  unsigned short l = f2bf(x - bf2f(h));
  dst[m * 131072 + i] = h;
  dst[m * 131072 + 65536 + i] = l;
}

// ---------------- kernel 2: projections ----------------
// p=0: q = Wq*x1 + bq  -> qt_hi/qt_lo, layout [b][n][c] bf16
// p=1: k = Wk*x2 + bk  -> kt_hi/kt_lo, layout [b][n][c] bf16
// p=2: v = Wv*x2 + bv  -> vv,          layout [b][c][n] bf16
// D[o][n] = sum_c W[o][c] * X[c][n]; A-frag = W (row-major, contiguous),
// B-frag = X gathered from LDS (natural [c][n] layout, padded row = 68).
#define PROW 68
__global__ __launch_bounds__(256) void proj_kernel(
    const float* __restrict__ x1, const float* __restrict__ x2,
    const unsigned short* __restrict__ wsp,
    const float* __restrict__ bq, const float* __restrict__ bk, const float* __restrict__ bv,
    unsigned short* __restrict__ qt_hi, unsigned short* __restrict__ qt_lo,
    unsigned short* __restrict__ kt_hi, unsigned short* __restrict__ kt_lo,
    unsigned short* __restrict__ vv) {
  __shared__ __align__(16) unsigned short sxh[256 * PROW];
  __shared__ __align__(16) unsigned short sxl[256 * PROW];
  const int t = threadIdx.x;
  const int n0 = blockIdx.x * 64;
  const int b = blockIdx.y;
  const int p = blockIdx.z;
  const float* x = (p == 0) ? x1 : x2;
  const float* bias = (p == 0) ? bq : ((p == 1) ? bk : bv);
  const unsigned short* wh = wsp + p * 131072;
  const unsigned short* wl = wh + 65536;

  // stage x tile [256][64] fp32 -> LDS bf16 hi/lo, natural [c][n] layout
  for (int it = 0; it < 16; ++it) {
    int chunk = t + 256 * it;      // 0..4095 float4 chunks
    int row = chunk >> 4, n4 = chunk & 15;
    float4 v4 = *((const float4*)(x + ((size_t)b * 256 + row) * 4096 + n0) + n4);
    float vals[4] = {v4.x, v4.y, v4.z, v4.w};
    unsigned short hh[4], ll[4];
    #pragma unroll
    for (int j = 0; j < 4; ++j) {
      hh[j] = f2bf(vals[j]);
      ll[j] = f2bf(vals[j] - bf2f(hh[j]));
    }
    int base = row * PROW + n4 * 4;
    *(ushort4*)(sxh + base) = make_ushort4(hh[0], hh[1], hh[2], hh[3]);
    *(ushort4*)(sxl + base) = make_ushort4(ll[0], ll[1], ll[2], ll[3]);
  }
  __syncthreads();

  const int w = t >> 6;
  const int lane = t & 63;
  const int li = lane & 15;
  const int lg = lane >> 4;
  const int nloc = w * 16 + li;       // this wave's n column (B-frag col)

  for (int ot = 0; ot < 16; ++ot) {
    f32x4 acc = 0.0f;
    const int ofr = ot * 16 + li;     // A-frag row (output channel o)
    #pragma unroll
    for (int cs = 0; cs < 8; ++cs) {
      s16x8 wfh = *(const s16x8*)(wh + ofr * 256 + cs * 32 + lg * 8);
      s16x8 wfl = *(const s16x8*)(wl + ofr * 256 + cs * 32 + lg * 8);
      s16x8 xfh, xfl;
      #pragma unroll
      for (int jj = 0; jj < 8; ++jj) {
        int cc = cs * 32 + lg * 8 + jj;
        xfh[jj] = (short)sxh[cc * PROW + nloc];
        xfl[jj] = (short)sxl[cc * PROW + nloc];
      }
      acc = mfma16(wfh, xfh, acc);   // hi*hi
      acc = mfma16(wfh, xfl, acc);   // hi*lo
      acc = mfma16(wfl, xfh, acc);   // lo*hi
    }
    int n = n0 + nloc;
    #pragma unroll
    for (int r = 0; r < 4; ++r) {
      int o = ot * 16 + lg * 4 + r;   // D row
      float val = acc[r] + bias[o];
      if (p == 2) {
        vv[((size_t)b * 256 + o) * 4096 + n] = f2bf(val);
      } else {
        unsigned short h = f2bf(val);
        unsigned short l2 = f2bf(val - bf2f(h));
        unsigned short* dh = (p == 0) ? qt_hi : kt_hi;
        unsigned short* dl = (p == 0) ? qt_lo : kt_lo;
        size_t idx = ((size_t)b * 4096 + n) * 256 + o;
        dh[idx] = h;
        dl[idx] = l2;
      }
    }
  }
}

// ---------------- kernel 3: flash attention ----------------
// grid (8 batches, 32 qblocks), 512 threads (8 waves x 16 queries each).
// Swapped QK^T: st = mfma(Kfrag, Qfrag) -> lane holds S[i=li][j=k0+16t+4lg+r].
// Online softmax with defer-max (THR=8). P permuted via 8 shuffles into the
// 16x16x32 B-frag; PV: out_tile = mfma(Vfrag, Pfrag).
__global__ __launch_bounds__(512, 2) void attn_kernel(
    const unsigned short* __restrict__ qt_hi, const unsigned short* __restrict__ qt_lo,
    const unsigned short* __restrict__ kt_hi, const unsigned short* __restrict__ kt_lo,
    const unsigned short* __restrict__ vv, float* __restrict__ out) {
  __shared__ __align__(16) unsigned short skh[32 * 256];  // K hi [row 512B] swizzled
  __shared__ __align__(16) unsigned short skl[32 * 256];  // K lo
  __shared__ __align__(16) unsigned short sv[256 * 32];   // V [c][m], row 64B swizzled

  const int tid = threadIdx.x;
  const int b = blockIdx.x;                 // batch -> XCD (linear%8 heuristic)
  const int w = tid >> 6;
  const int lane = tid & 63;
  const int li = lane & 15;
  const int lg = lane >> 4;
  const int q0 = blockIdx.y * 128 + w * 16;

  // Q fragments: 16 queries x 256 channels, hi/lo (64 VGPRs)
  s16x8 qh[8], ql[8];
  {
    const size_t qrow = ((size_t)b * N_DIM + q0 + li) * C_DIM;
    #pragma unroll
    for (int cs = 0; cs < 8; ++cs) {
      qh[cs] = *(const s16x8*)(qt_hi + qrow + cs * 32 + lg * 8);
      ql[cs] = *(const s16x8*)(qt_lo + qrow + cs * 32 + lg * 8);
    }
  }

  f32x4 acc[16];
  #pragma unroll
  for (int ct = 0; ct < 16; ++ct) acc[ct] = 0.0f;
  float m_run = -1e30f, l_run = 0.f;

  for (int kt = 0; kt < N_DIM / 32; ++kt) {
    const int k0 = kt * 32;
    __syncthreads();
    // stage K hi/lo (32x256) + V (256x32), XOR-swizzled
    #pragma unroll
    for (int r = 0; r < 2; ++r) {
      int chunk = tid + 512 * r;            // 0..1023
      int row = chunk >> 5, o16 = chunk & 31;
      size_t g = ((size_t)b * N_DIM + k0 + row) * C_DIM + o16 * 8;
      int lb = row * 512 + ((o16 * 16) ^ ((row & 7) << 4));
      *(int4*)((char*)skh + lb) = *(const int4*)(kt_hi + g);
      *(int4*)((char*)skl + lb) = *(const int4*)(kt_lo + g);
      int c = chunk >> 2, o4 = chunk & 3;
      size_t gv = ((size_t)b * C_DIM + c) * N_DIM + k0 + o4 * 8;
      int lbv = c * 64 + ((o4 * 16) ^ ((c & 3) << 4));
      *(int4*)((char*)sv + lbv) = *(const int4*)(vv + gv);
    }
    __syncthreads();

    // QK^T (swapped, hi/lo 3-term): st[t2] lane holds S[i=li][j=k0+16*t2+4*lg+r]
    f32x4 st[2];
    st[0] = 0.0f; st[1] = 0.0f;
    #pragma unroll
    for (int cs = 0; cs < 8; ++cs) {
      #pragma unroll
      for (int t2 = 0; t2 < 2; ++t2) {
        int row = t2 * 16 + li;
        int off = row * 512 + ((cs * 64 + lg * 16) ^ ((row & 7) << 4));
        s16x8 kh = *(const s16x8*)((const char*)skh + off);
        s16x8 kl = *(const s16x8*)((const char*)skl + off);
        st[t2] = mfma16(kh, qh[cs], st[t2]);
        st[t2] = mfma16(kh, ql[cs], st[t2]);
        st[t2] = mfma16(kl, qh[cs], st[t2]);
      }
    }

    // online softmax (defer-max, THR=8)
    float s0 = st[0][0], s1 = st[0][1], s2 = st[0][2], s3 = st[0][3];
    float s4 = st[1][0], s5 = st[1][1], s6 = st[1][2], s7 = st[1][3];
    float tmax = fmaxf(fmaxf(fmaxf(s0, s1), fmaxf(s2, s3)),
                       fmaxf(fmaxf(s4, s5), fmaxf(s6, s7)));
    tmax = fmaxf(tmax, __shfl_xor(tmax, 16));
    tmax = fmaxf(tmax, __shfl_xor(tmax, 32));
    if (tmax > m_run + 8.0f) {
      float sc = __expf(m_run - tmax);
      m_run = tmax;
      l_run *= sc;
      #pragma unroll
      for (int ct = 0; ct < 16; ++ct) {
        acc[ct][0] *= sc; acc[ct][1] *= sc; acc[ct][2] *= sc; acc[ct][3] *= sc;
      }
    }
    float e0 = __expf(s0 - m_run), e1 = __expf(s1 - m_run);
    float e2 = __expf(s2 - m_run), e3 = __expf(s3 - m_run);
    float e4 = __expf(s4 - m_run), e5 = __expf(s5 - m_run);
    float e6 = __expf(s6 - m_run), e7 = __expf(s7 - m_run);
    float ts = ((e0 + e1) + (e2 + e3)) + ((e4 + e5) + (e6 + e7));
    ts += __shfl_xor(ts, 16);
    ts += __shfl_xor(ts, 32);
    l_run += ts;

    // pack P -> bf16 dwords; lane (li,lg) holds tile-t dwords {8t+2lg, 8t+2lg+1}
    unsigned int W00 = (unsigned int)f2bf(e0) | ((unsigned int)f2bf(e1) << 16);
    unsigned int W01 = (unsigned int)f2bf(e2) | ((unsigned int)f2bf(e3) << 16);
    unsigned int W10 = (unsigned int)f2bf(e4) | ((unsigned int)f2bf(e5) << 16);
    unsigned int W11 = (unsigned int)f2bf(e6) | ((unsigned int)f2bf(e7) << 16);
    // permute to B-frag: lane needs dwords D = 4*lg + {0..3} of the 32-key block
    int srcA = li + 32 * (lg & 1);
    int srcB = srcA + 16;
    unsigned int a00 = __shfl(W00, srcA), a01 = __shfl(W01, srcA);
    unsigned int a10 = __shfl(W10, srcA), a11 = __shfl(W11, srcA);
    unsigned int b00 = __shfl(W00, srcB), b01 = __shfl(W01, srcB);
    unsigned int b10 = __shfl(W10, srcB), b11 = __shfl(W11, srcB);
    bool h2 = (lg >> 1) != 0;
    union { unsigned int u[4]; s16x8 v; } pu;
    pu.u[0] = h2 ? a10 : a00;
    pu.u[1] = h2 ? a11 : a01;
    pu.u[2] = h2 ? b10 : b00;
    pu.u[3] = h2 ? b11 : b01;

    // PV: acc[ct] += V_tile * P^T  (A-frag = V[c][m], B-frag = P)
    #pragma unroll
    for (int ct = 0; ct < 16; ++ct) {
      int c = ct * 16 + li;
      int lbv = c * 64 + ((lg * 16) ^ ((c & 3) << 4));
      s16x8 vf = *(const s16x8*)((const char*)sv + lbv);
      acc[ct] = mfma16(vf, pu.v, acc[ct]);
    }
  }

  // epilogue: normalize and store out[b][c][n] fp32
  float inv = 1.0f / l_run;
  #pragma unroll
  for (int ct = 0; ct < 16; ++ct) {
    #pragma unroll
    for (int r = 0; r < 4; ++r) {
      int c = ct * 16 + lg * 4 + r;
      out[((size_t)b * C_DIM + c) * N_DIM + q0 + li] = acc[ct][r] * inv;
    }
  }
}

extern "C" void kernel_launch(void* const* d_in, const int* in_sizes, int n_in,
                              void* d_out, int out_size, void* d_ws, size_t ws_size,
                              hipStream_t stream) {
  const float* x1 = (const float*)d_in[0];
  const float* x2 = (const float*)d_in[1];
  const float* Wq = (const float*)d_in[2];
  const float* bq = (const float*)d_in[3];
  const float* Wk = (const float*)d_in[4];
  const float* bk = (const float*)d_in[5];
  const float* Wv = (const float*)d_in[6];
  const float* bv = (const float*)d_in[7];
  float* out = (float*)d_out;

  char* ws = (char*)d_ws;
  const size_t SZ = (size_t)8 * 4096 * 256 * 2;  // 16.78 MB per bf16 plane
  unsigned short* qt_hi = (unsigned short*)(ws + 0 * SZ);
  unsigned short* qt_lo = (unsigned short*)(ws + 1 * SZ);
  unsigned short* kt_hi = (unsigned short*)(ws + 2 * SZ);
  unsigned short* kt_lo = (unsigned short*)(ws + 3 * SZ);
  unsigned short* vv    = (unsigned short*)(ws + 4 * SZ);
  unsigned short* wsp   = (unsigned short*)(ws + 5 * SZ);  // 3*2*65536 shorts
  // requires ws_size >= 5*SZ + 786432 = 84,672,512 bytes

  split_w3<<<dim3(256, 3), 256, 0, stream>>>(Wq, Wk, Wv, wsp);
  proj_kernel<<<dim3(64, 8, 3), 256, 0, stream>>>(x1, x2, wsp, bq, bk, bv,
                                                  qt_hi, qt_lo, kt_hi, kt_lo, vv);
  attn_kernel<<<dim3(8, 32), 512, 0, stream>>>(qt_hi, qt_lo, kt_hi, kt_lo, vv, out);
}